// Round 5
// baseline (645.730 us; speedup 1.0000x reference)
//
#include <hip/hip_runtime.h>
#include <hip/hip_bf16.h>
#include <cstdint>

#define DEV __device__ __forceinline__

typedef __attribute__((ext_vector_type(8))) short short8;
typedef __attribute__((ext_vector_type(4))) float f32x4;
typedef __attribute__((ext_vector_type(4))) unsigned short us4;
typedef __attribute__((ext_vector_type(8))) unsigned short us8;

DEV unsigned short f2bf(float x) {
    unsigned int u = __float_as_uint(x);
    unsigned int r = (u + 0x7FFFu + ((u >> 16) & 1u)) >> 16;
    return (unsigned short)r;
}
DEV float bf2f(unsigned short h) { return __uint_as_float(((unsigned int)h) << 16); }

// async global->LDS, 16B per lane; LDS dest is wave-uniform base + lane*16 (HW rule)
DEV void gld_lds16(const unsigned short* g, unsigned short* l) {
    __builtin_amdgcn_global_load_lds(
        (const __attribute__((address_space(1))) unsigned int*)g,
        (__attribute__((address_space(3))) unsigned int*)l, 16, 0, 0);
}

// problem sizes
#define LL 4096
#define DM 256
#define DH 128
#define SB_TOT 8       // 2 streams * 4 batch
#define CH1 32         // scan chunk length
#define NCH 128        // LL / CH1
#define LOG2E 1.44269504088896f
#define NBLK 512

// manual grid barrier: all 512 blocks guaranteed co-resident (launch_bounds(256,2)
// caps VGPR at 256 -> 2 waves/SIMD; LDS 40KB*2=80KB <= 160KB -> capacity >= 2 blk/CU).
// Device-scope atomics + threadfence handle cross-XCD L2 non-coherence.
DEV void gbar(unsigned int* cnt, int idx) {
    __syncthreads();
    if (threadIdx.x == 0) {
        __threadfence();
        __hip_atomic_fetch_add(&cnt[idx], 1u, __ATOMIC_ACQ_REL, __HIP_MEMORY_SCOPE_AGENT);
        while (__hip_atomic_load(&cnt[idx], __ATOMIC_ACQUIRE, __HIP_MEMORY_SCOPE_AGENT) < (unsigned)NBLK) {
            __builtin_amdgcn_s_sleep(4);
        }
        __threadfence();
    }
    __syncthreads();
}

__global__ __launch_bounds__(64) void bar_init(unsigned int* cnt) {
    if (threadIdx.x < 16) cnt[threadIdx.x] = 0u;
}

// LDS union across phases (max member 40KB -> 2 blocks/CU resident)
union SMU {
    struct { unsigned short As[128 * 32]; unsigned short Bs[128 * 32]; } g;   // 16KB (gemm)
    struct { unsigned short As[64 * 136]; } c;                                // 17.4KB (convproj)
    struct { float b_s[2][512]; float c_s[2][512];                            // 8KB (scan, persistent P3->P5)
             float Ps[2][2048]; float Hs[2][2048]; } s;                       // +32KB (P4)
};

// ---------------- bf16 MFMA GEMM phase (m97 structure): C = A[M,256] * B[256,256]^T ----------------
// blk in [0,512): m0=(blk>>1)*128, n0=(blk&1)*128.
template<int F32OUT>
DEV void gemm_phase(SMU* sm, int blk, int t,
                    const unsigned short* A, const unsigned short* B,
                    float* Cf, unsigned short* Cb)
{
    unsigned short* As = sm->g.As;
    unsigned short* Bs = sm->g.Bs;
    const int m0 = (blk >> 1) * 128, n0 = (blk & 1) * 128;
    const int lane = t & 63, wv = t >> 6;
    const int wm = (wv & 1) * 64, wn = (wv >> 1) * 64;
    const int lr = lane & 15, lk = (lane >> 4) * 8;
    const int srow = lane >> 2, scol = (lane & 3) * 8;

    f32x4 acc[4][4] = {};
    for (int kt = 0; kt < 8; ++kt) {
        const int k0 = kt * 32;
        #pragma unroll
        for (int h = 0; h < 2; ++h) {
            const int c = wv + h * 4;
            const unsigned short* ga = A + (size_t)(m0 + c * 16 + srow) * 256 + k0 + scol;
            const unsigned short* gb = B + (size_t)(n0 + c * 16 + srow) * 256 + k0 + scol;
            gld_lds16(ga, &As[c * 512]);
            gld_lds16(gb, &Bs[c * 512]);
        }
        __syncthreads();
        short8 av[4], bv[4];
        #pragma unroll
        for (int i = 0; i < 4; ++i) av[i] = *(const short8*)&As[(wm + i * 16 + lr) * 32 + lk];
        #pragma unroll
        for (int i = 0; i < 4; ++i) bv[i] = *(const short8*)&Bs[(wn + i * 16 + lr) * 32 + lk];
        #pragma unroll
        for (int i = 0; i < 4; ++i)
            #pragma unroll
            for (int j = 0; j < 4; ++j)
                acc[i][j] = __builtin_amdgcn_mfma_f32_16x16x32_bf16(av[i], bv[j], acc[i][j], 0, 0, 0);
        __syncthreads();
    }
    #pragma unroll
    for (int i = 0; i < 4; ++i) {
        #pragma unroll
        for (int j = 0; j < 4; ++j) {
            int r0 = m0 + wm + i * 16 + (lane >> 4) * 4;
            int cc = n0 + wn + j * 16 + lr;
            #pragma unroll
            for (int r = 0; r < 4; ++r) {
                float v = acc[i][j][r];
                if (F32OUT) Cf[(size_t)(r0 + r) * 256 + cc] = v;
                else        Cb[(size_t)(r0 + r) * 256 + cc] = f2bf(v);
            }
        }
    }
}

// ---------------- single persistent kernel: entire pipeline, 512 blocks x 256 thr ----------------
__global__ __launch_bounds__(256, 2) void mamba_all(
    const float* u0, const float* u1, const float* inw,
    const float* cxw, const float* czw, const float* xpw,
    const float* dtw, const float* dtb, const float* alog,
    const float* Dp, const float* outw,
    unsigned short* ubf, unsigned short* wbi, unsigned short* wbo,
    unsigned short* Wb, unsigned short* xzbf, float* xf,
    unsigned short* catb, float* delta, float* BC,
    float* P, float* H, float* outp, unsigned int* cnt)
{
    const int t = threadIdx.x;
    const int b = blockIdx.x;
    __shared__ __align__(16) SMU sm;

    // ======== P0: prep (fp32->bf16 u/in_proj/out_proj + fused Wb) ========
    for (int it = 0; it < 17; ++it) {
        int i = (b * 256 + t + it * 131072) * 4;
        if (i >= 8540160) break;
        if (i < 4194304) {
            f32x4 v = *(const f32x4*)&u0[i];
            us4 r = { f2bf(v.x), f2bf(v.y), f2bf(v.z), f2bf(v.w) };
            *(us4*)&ubf[i] = r;
        } else if (i < 8388608) {
            int j = i - 4194304;
            f32x4 v = *(const f32x4*)&u1[j];
            us4 r = { f2bf(v.x), f2bf(v.y), f2bf(v.z), f2bf(v.w) };
            *(us4*)&ubf[4194304 + j] = r;
        } else if (i < 8454144) {
            int j = i - 8388608;
            f32x4 v = *(const f32x4*)&inw[j];
            us4 r = { f2bf(v.x), f2bf(v.y), f2bf(v.z), f2bf(v.w) };
            *(us4*)&wbi[j] = r;
        } else if (i < 8519680) {
            int j = i - 8454144;
            f32x4 v = *(const f32x4*)&outw[j];
            us4 r = { f2bf(v.x), f2bf(v.y), f2bf(v.z), f2bf(v.w) };
            *(us4*)&wbo[j] = r;
        } else {
            int j = i - 8519680;            // 0..20476, step 4
            int n = j >> 7, k0 = j & 127;
            if (n < 128) {
                float a0 = 0.f, a1 = 0.f, a2 = 0.f, a3 = 0.f;
                const float* dw = dtw + n * 16;
                #pragma unroll
                for (int r = 0; r < 16; ++r) {
                    float w = dw[r];
                    const float* xr = xpw + r * 128 + k0;
                    a0 = fmaf(w, xr[0], a0);
                    a1 = fmaf(w, xr[1], a1);
                    a2 = fmaf(w, xr[2], a2);
                    a3 = fmaf(w, xr[3], a3);
                }
                us4 rr = { f2bf(a0), f2bf(a1), f2bf(a2), f2bf(a3) };
                *(us4*)&Wb[n * 128 + k0] = rr;
            } else {
                f32x4 v = *(const f32x4*)&xpw[(n - 112) * 128 + k0];
                us4 rr = { f2bf(v.x), f2bf(v.y), f2bf(v.z), f2bf(v.w) };
                *(us4*)&Wb[n * 128 + k0] = rr;
            }
        }
    }
    gbar(cnt, 0);

    // ======== P1: in_proj GEMM -> xzbf ========
    gemm_phase<0>(&sm, b, t, ubf, wbi, nullptr, xzbf);
    gbar(cnt, 1);

    // ======== P2: depthwise conv + SiLU + x_proj/dt_proj MFMA + softplus ========
    {
        const int m0 = b * 64;
        #pragma unroll
        for (int i = 0; i < 8; ++i) {
            int s = t + i * 256;
            int r = s >> 5, g = s & 31;
            int gr = m0 + r;
            int l = gr & 4095;
            int c; const float* wp; const unsigned short* bp;
            if (g < 16) { c = g * 8;        wp = cxw; bp = xzbf + (size_t)gr * 256 + c; }
            else        { c = (g - 16) * 8; wp = czw; bp = xzbf + (size_t)gr * 256 + 128 + c; }
            us8 zz = (us8)0;
            us8 vm = (l > 0)    ? *(const us8*)(bp - 256) : zz;
            us8 v0 = *(const us8*)bp;
            us8 vp = (l < 4095) ? *(const us8*)(bp + 256) : zz;
            float o[8];
            #pragma unroll
            for (int j = 0; j < 8; ++j) {
                int cc = c + j;
                float v = bf2f(vm[j]) * wp[cc * 3] + bf2f(v0[j]) * wp[cc * 3 + 1]
                        + bf2f(vp[j]) * wp[cc * 3 + 2];
                v = v / (1.f + __expf(-v));
                o[j] = v;
            }
            us8 rb8 = { f2bf(o[0]), f2bf(o[1]), f2bf(o[2]), f2bf(o[3]),
                        f2bf(o[4]), f2bf(o[5]), f2bf(o[6]), f2bf(o[7]) };
            if (g < 16) {
                *(us8*)&sm.c.As[r * 136 + c] = rb8;
                *(f32x4*)&xf[(size_t)gr * 128 + c]     = *(f32x4*)&o[0];
                *(f32x4*)&xf[(size_t)gr * 128 + c + 4] = *(f32x4*)&o[4];
            } else {
                *(us8*)&catb[(size_t)gr * 256 + 128 + c] = rb8;
            }
        }
        __syncthreads();
        const int lane = t & 63, wv = t >> 6;
        const int lr = lane & 15, lk = (lane >> 4) * 8;
        f32x4 acc[10] = {};
        #pragma unroll
        for (int kt = 0; kt < 4; ++kt) {
            const int k0 = kt * 32;
            short8 av = *(const short8*)&sm.c.As[(wv * 16 + lr) * 136 + k0 + lk];
            #pragma unroll
            for (int j = 0; j < 10; ++j) {
                short8 bv = *(const short8*)(Wb + (j * 16 + lr) * 128 + k0 + lk);
                acc[j] = __builtin_amdgcn_mfma_f32_16x16x32_bf16(av, bv, acc[j], 0, 0, 0);
            }
        }
        const int r0 = (lane >> 4) * 4;
        #pragma unroll
        for (int j = 0; j < 10; ++j) {
            int col = j * 16 + lr;
            #pragma unroll
            for (int r = 0; r < 4; ++r) {
                float v = acc[j][r];
                size_t row = (size_t)m0 + wv * 16 + r0 + r;
                if (j < 8) {
                    float x = v + dtb[col];
                    float sp = (x > 20.f) ? x : log1pf(__expf(x));
                    delta[row * 128 + col] = sp;
                } else {
                    BC[row * 32 + (col - 128)] = v;
                }
            }
        }
    }
    gbar(cnt, 2);

    // ======== P3: scan local (per-chunk, h from 0); dt/u kept in registers ========
    const int hh = t >> 7, tl = t & 127;
    const int task = 2 * b + hh;                 // (sb, ch)
    const int sb = task >> 7, ch = task & 127;
    const size_t rb = (size_t)sb * LL + (size_t)ch * CH1;
    float dtr[32], ur[32];
    {
        int row = tl >> 2, c4 = (tl & 3) * 4;
        *(f32x4*)&sm.s.b_s[hh][row * 16 + c4] = *(const f32x4*)&BC[(rb + row) * 32 + c4];
        *(f32x4*)&sm.s.c_s[hh][row * 16 + c4] = *(const f32x4*)&BC[(rb + row) * 32 + 16 + c4];
    }
    #pragma unroll
    for (int i = 0; i < 32; ++i) dtr[i] = delta[(rb + i) * DH + tl];
    #pragma unroll
    for (int i = 0; i < 32; ++i) ur[i] = xf[(rb + i) * DH + tl];
    __syncthreads();
    {
        float Ar[16];
        #pragma unroll
        for (int n = 0; n < 16; ++n) Ar[n] = -__expf(alog[tl * 16 + n]) * LOG2E;
        float h[16], p[16];
        #pragma unroll
        for (int n = 0; n < 16; ++n) { h[n] = 0.f; p[n] = 1.f; }
        for (int i = 0; i < CH1; ++i) {
            float dt = dtr[i];
            float du = dt * ur[i];
            float bl[16];
            *(f32x4*)&bl[0]  = *(const f32x4*)&sm.s.b_s[hh][i * 16];
            *(f32x4*)&bl[4]  = *(const f32x4*)&sm.s.b_s[hh][i * 16 + 4];
            *(f32x4*)&bl[8]  = *(const f32x4*)&sm.s.b_s[hh][i * 16 + 8];
            *(f32x4*)&bl[12] = *(const f32x4*)&sm.s.b_s[hh][i * 16 + 12];
            #pragma unroll
            for (int n = 0; n < 16; ++n) {
                float a = exp2f(dt * Ar[n]);
                h[n] = fmaf(a, h[n], du * bl[n]);
                p[n] *= a;
            }
        }
        size_t ob = (((size_t)sb * NCH + ch) * 128 + tl) * 16;
        #pragma unroll
        for (int n4 = 0; n4 < 16; n4 += 4) {
            f32x4 pv = { p[n4], p[n4 + 1], p[n4 + 2], p[n4 + 3] };
            f32x4 hv = { h[n4], h[n4 + 1], h[n4 + 2], h[n4 + 3] };
            *(f32x4*)&P[ob + n4] = pv;
            *(f32x4*)&H[ob + n4] = hv;
        }
    }
    gbar(cnt, 3);

    // ======== P4: prefix over chunks; H becomes h_init of each chunk ========
    {
        const int sb2 = task >> 7, d2 = task & 127;  // task reused as (sb, d)
        size_t g0 = (((size_t)sb2 * NCH + tl) * 128 + d2) * 16;
        #pragma unroll
        for (int n4 = 0; n4 < 16; n4 += 4) {
            *(f32x4*)&sm.s.Ps[hh][tl * 16 + n4] = *(const f32x4*)&P[g0 + n4];
            *(f32x4*)&sm.s.Hs[hh][tl * 16 + n4] = *(const f32x4*)&H[g0 + n4];
        }
        __syncthreads();
        if (tl < 16) {
            float hin = 0.f;
            for (int c2 = 0; c2 < NCH; ++c2) {
                float pp = sm.s.Ps[hh][c2 * 16 + tl];
                float hl = sm.s.Hs[hh][c2 * 16 + tl];
                sm.s.Hs[hh][c2 * 16 + tl] = hin;
                hin = fmaf(pp, hin, hl);
            }
        }
        __syncthreads();
        #pragma unroll
        for (int n4 = 0; n4 < 16; n4 += 4)
            *(f32x4*)&H[g0 + n4] = *(const f32x4*)&sm.s.Hs[hh][tl * 16 + n4];
    }
    gbar(cnt, 4);

    // ======== P5: replay with h_init; y -> catb cols 0..127 ========
    {
        float Ar[16];
        #pragma unroll
        for (int n = 0; n < 16; ++n) Ar[n] = -__expf(alog[tl * 16 + n]) * LOG2E;
        float Dv = Dp[tl];
        size_t ob = (((size_t)sb * NCH + ch) * 128 + tl) * 16;
        float h[16];
        #pragma unroll
        for (int n4 = 0; n4 < 16; n4 += 4) {
            f32x4 hv = *(const f32x4*)&H[ob + n4];
            h[n4] = hv.x; h[n4 + 1] = hv.y; h[n4 + 2] = hv.z; h[n4 + 3] = hv.w;
        }
        for (int i = 0; i < CH1; ++i) {
            float dt = dtr[i];
            float uu = ur[i];
            float du = dt * uu;
            float bl[16], cl[16];
            *(f32x4*)&bl[0]  = *(const f32x4*)&sm.s.b_s[hh][i * 16];
            *(f32x4*)&bl[4]  = *(const f32x4*)&sm.s.b_s[hh][i * 16 + 4];
            *(f32x4*)&bl[8]  = *(const f32x4*)&sm.s.b_s[hh][i * 16 + 8];
            *(f32x4*)&bl[12] = *(const f32x4*)&sm.s.b_s[hh][i * 16 + 12];
            *(f32x4*)&cl[0]  = *(const f32x4*)&sm.s.c_s[hh][i * 16];
            *(f32x4*)&cl[4]  = *(const f32x4*)&sm.s.c_s[hh][i * 16 + 4];
            *(f32x4*)&cl[8]  = *(const f32x4*)&sm.s.c_s[hh][i * 16 + 8];
            *(f32x4*)&cl[12] = *(const f32x4*)&sm.s.c_s[hh][i * 16 + 12];
            float y0 = uu * Dv, y1 = 0.f, y2 = 0.f, y3 = 0.f;
            #pragma unroll
            for (int n = 0; n < 16; n += 4) {
                float a0 = exp2f(dt * Ar[n]);
                float a1 = exp2f(dt * Ar[n + 1]);
                float a2 = exp2f(dt * Ar[n + 2]);
                float a3 = exp2f(dt * Ar[n + 3]);
                h[n]     = fmaf(a0, h[n],     du * bl[n]);
                h[n + 1] = fmaf(a1, h[n + 1], du * bl[n + 1]);
                h[n + 2] = fmaf(a2, h[n + 2], du * bl[n + 2]);
                h[n + 3] = fmaf(a3, h[n + 3], du * bl[n + 3]);
                y0 = fmaf(h[n],     cl[n],     y0);
                y1 = fmaf(h[n + 1], cl[n + 1], y1);
                y2 = fmaf(h[n + 2], cl[n + 2], y2);
                y3 = fmaf(h[n + 3], cl[n + 3], y3);
            }
            float y = (y0 + y1) + (y2 + y3);
            catb[(rb + i) * DM + tl] = f2bf(y);
        }
    }
    gbar(cnt, 5);

    // ======== P6: out_proj GEMM -> outp (only write to d_out) ========
    gemm_phase<1>(&sm, b, t, catb, wbo, outp, nullptr);
}

extern "C" void kernel_launch(void* const* d_in, const int* in_sizes, int n_in,
                              void* d_out, int out_size, void* d_ws, size_t ws_size,
                              hipStream_t stream) {
    const float* u0   = (const float*)d_in[0];
    const float* u1   = (const float*)d_in[1];
    const float* inw  = (const float*)d_in[2];
    const float* cxw  = (const float*)d_in[3];
    const float* czw  = (const float*)d_in[4];
    const float* xpw  = (const float*)d_in[5];
    const float* dtw  = (const float*)d_in[6];
    const float* dtb  = (const float*)d_in[7];
    const float* alog = (const float*)d_in[8];
    const float* Dp   = (const float*)d_in[9];
    const float* outw = (const float*)d_in[10];

    // Workspace layout (phase-ordered aliasing inside ONE kernel; aliased pairs
    // are accessed in different barrier-separated phases):
    //   [0 : 16.8M]      ubf (P0->P1), then delta (P2..P5)
    //   [16.8M : 33.6M]  xzbf (P1->P2), then P[16.8:25.2M] + H[25.2:33.6M] (P3..P5)
    //   [33.6M : 50.3M]  xf f32 (P2..P3)
    //   [50.3M : 54.5M]  BC (P2..P3)
    //   [54.5M : 71.3M]  catb (P2/P5 -> P6)
    //   [71.3M : +303K]  wbi, wbo, Wb, barrier counters
    char* ws = (char*)d_ws;
    unsigned short* ubf  = (unsigned short*)(ws + 0);
    float* delta         = (float*)(ws + 0);
    unsigned short* xzbf = (unsigned short*)(ws + 16777216);
    float* P             = (float*)(ws + 16777216);
    float* H             = (float*)(ws + 25165824);
    float* xf            = (float*)(ws + 33554432);
    float* BC            = (float*)(ws + 50331648);
    unsigned short* catb = (unsigned short*)(ws + 54525952);
    unsigned short* wbi  = (unsigned short*)(ws + 71303168);
    unsigned short* wbo  = (unsigned short*)(ws + 71434240);
    unsigned short* Wb   = (unsigned short*)(ws + 71565312);
    unsigned int*   cnt  = (unsigned int*)(ws + 71606272);

    float* outp = (float*)d_out;

    bar_init<<<1, 64, 0, stream>>>(cnt);
    mamba_all<<<NBLK, 256, 0, stream>>>(
        u0, u1, inw, cxw, czw, xpw, dtw, dtb, alog, Dp, outw,
        ubf, wbi, wbo, Wb, xzbf, xf, catb, delta, BC,
        (float*)P, (float*)H, outp, cnt);
}

// Round 6
// 219.900 us; speedup vs baseline: 2.9365x; 2.9365x over previous
//
#include <hip/hip_runtime.h>
#include <hip/hip_bf16.h>
#include <cstdint>

#define DEV __device__ __forceinline__

typedef __attribute__((ext_vector_type(8))) short short8;
typedef __attribute__((ext_vector_type(4))) float f32x4;
typedef __attribute__((ext_vector_type(4))) unsigned short us4;
typedef __attribute__((ext_vector_type(8))) unsigned short us8;

DEV unsigned short f2bf(float x) {
    unsigned int u = __float_as_uint(x);
    unsigned int r = (u + 0x7FFFu + ((u >> 16) & 1u)) >> 16;
    return (unsigned short)r;
}
DEV float bf2f(unsigned short h) { return __uint_as_float(((unsigned int)h) << 16); }

// async global->LDS, 16B per lane; LDS dest is wave-uniform base + lane*16 (HW rule)
DEV void gld_lds16(const unsigned short* g, unsigned short* l) {
    __builtin_amdgcn_global_load_lds(
        (const __attribute__((address_space(1))) unsigned int*)g,
        (__attribute__((address_space(3))) unsigned int*)l, 16, 0, 0);
}

// problem sizes
#define LL 4096
#define DM 256
#define DH 128
#define SB_TOT 8       // 2 streams * 4 batch
#define CH1 32         // scan chunk length
#define NCH 128        // LL / CH1
#define LOG2E 1.44269504088896f

// ---------------- prep: fp32 -> bf16 (u, in_proj, out_proj) + fused proj weight Wb ----------------
// Wb[160][128] bf16:
//   n <  128 : Wb[n][k] = sum_r dtw[n][r] * xw[r][k]      (dt_proj folded into x_proj)
//   n >= 128 : Wb[n][k] = xw[16 + (n-128)][k]             (B and C rows)
__global__ __launch_bounds__(256) void prep_kernel(
    const float* __restrict__ u0, const float* __restrict__ u1,
    const float* __restrict__ inw, const float* __restrict__ outw,
    const float* __restrict__ xpw, const float* __restrict__ dtw,
    unsigned short* __restrict__ ubf, unsigned short* __restrict__ wbi,
    unsigned short* __restrict__ wbo, unsigned short* __restrict__ Wb)
{
    int gid = blockIdx.x * 256 + threadIdx.x;
    int i = gid * 4;
    if (i < 4194304) {
        f32x4 v = *(const f32x4*)&u0[i];
        us4 r = { f2bf(v.x), f2bf(v.y), f2bf(v.z), f2bf(v.w) };
        *(us4*)&ubf[i] = r;
    } else if (i < 8388608) {
        int j = i - 4194304;
        f32x4 v = *(const f32x4*)&u1[j];
        us4 r = { f2bf(v.x), f2bf(v.y), f2bf(v.z), f2bf(v.w) };
        *(us4*)&ubf[4194304 + j] = r;
    } else if (i < 8454144) {
        int j = i - 8388608;
        f32x4 v = *(const f32x4*)&inw[j];
        us4 r = { f2bf(v.x), f2bf(v.y), f2bf(v.z), f2bf(v.w) };
        *(us4*)&wbi[j] = r;
    } else if (i < 8519680) {
        int j = i - 8454144;
        f32x4 v = *(const f32x4*)&outw[j];
        us4 r = { f2bf(v.x), f2bf(v.y), f2bf(v.z), f2bf(v.w) };
        *(us4*)&wbo[j] = r;
    } else if (i < 8540160) {
        int j = i - 8519680;            // 0..20476, step 4
        int n = j >> 7, k0 = j & 127;
        if (n < 128) {
            float a0 = 0.f, a1 = 0.f, a2 = 0.f, a3 = 0.f;
            const float* dw = dtw + n * 16;
            #pragma unroll
            for (int r = 0; r < 16; ++r) {
                float w = dw[r];
                const float* xr = xpw + r * 128 + k0;
                a0 = fmaf(w, xr[0], a0);
                a1 = fmaf(w, xr[1], a1);
                a2 = fmaf(w, xr[2], a2);
                a3 = fmaf(w, xr[3], a3);
            }
            us4 rr = { f2bf(a0), f2bf(a1), f2bf(a2), f2bf(a3) };
            *(us4*)&Wb[n * 128 + k0] = rr;
        } else {
            f32x4 v = *(const f32x4*)&xpw[(n - 112) * 128 + k0];
            us4 rr = { f2bf(v.x), f2bf(v.y), f2bf(v.z), f2bf(v.w) };
            *(us4*)&Wb[n * 128 + k0] = rr;
        }
    }
}

// ---------------- bf16 MFMA GEMM (m97 structure): C[M,N] = A[M,K] * B[N,K]^T, K=N=256 ----------------
template<int F32OUT>
__global__ __launch_bounds__(256) void gemm_bt(
    const unsigned short* __restrict__ A, const unsigned short* __restrict__ B,
    float* __restrict__ Cf, unsigned short* __restrict__ Cb)
{
    __shared__ __align__(16) unsigned short As[128 * 32];
    __shared__ __align__(16) unsigned short Bs[128 * 32];
    const int t = threadIdx.x;
    const int m0 = blockIdx.x * 128, n0 = blockIdx.y * 128;
    const int lane = t & 63, wv = t >> 6;
    const int wm = (wv & 1) * 64, wn = (wv >> 1) * 64;
    const int lr = lane & 15, lk = (lane >> 4) * 8;
    const int srow = lane >> 2, scol = (lane & 3) * 8;

    f32x4 acc[4][4] = {};
    for (int kt = 0; kt < 8; ++kt) {
        const int k0 = kt * 32;
        #pragma unroll
        for (int h = 0; h < 2; ++h) {
            const int c = wv + h * 4;
            const unsigned short* ga = A + (size_t)(m0 + c * 16 + srow) * 256 + k0 + scol;
            const unsigned short* gb = B + (size_t)(n0 + c * 16 + srow) * 256 + k0 + scol;
            gld_lds16(ga, &As[c * 512]);
            gld_lds16(gb, &Bs[c * 512]);
        }
        __syncthreads();
        short8 av[4], bv[4];
        #pragma unroll
        for (int i = 0; i < 4; ++i) av[i] = *(const short8*)&As[(wm + i * 16 + lr) * 32 + lk];
        #pragma unroll
        for (int i = 0; i < 4; ++i) bv[i] = *(const short8*)&Bs[(wn + i * 16 + lr) * 32 + lk];
        #pragma unroll
        for (int i = 0; i < 4; ++i)
            #pragma unroll
            for (int j = 0; j < 4; ++j)
                acc[i][j] = __builtin_amdgcn_mfma_f32_16x16x32_bf16(av[i], bv[j], acc[i][j], 0, 0, 0);
        __syncthreads();
    }
    #pragma unroll
    for (int i = 0; i < 4; ++i) {
        #pragma unroll
        for (int j = 0; j < 4; ++j) {
            int r0 = m0 + wm + i * 16 + (lane >> 4) * 4;
            int cc = n0 + wn + j * 16 + lr;
            #pragma unroll
            for (int r = 0; r < 4; ++r) {
                float v = acc[i][j][r];
                if (F32OUT) Cf[(size_t)(r0 + r) * 256 + cc] = v;
                else        Cb[(size_t)(r0 + r) * 256 + cc] = f2bf(v);
            }
        }
    }
}

// ---------------- fused depthwise conv + SiLU + x_proj/dt_proj MFMA + softplus ----------------
// FUSE_SCAN=1 additionally runs scan phase-1 (local chunk scan) for this block's
// 2 chunks: delta/xf re-read from L2-warm global, B rows from LDS; writes P,H.
template<int FUSE_SCAN>
__global__ __launch_bounds__(256) void convproj_k(
    const unsigned short* __restrict__ xz, const unsigned short* __restrict__ Wb,
    const float* __restrict__ wx, const float* __restrict__ wz,
    const float* __restrict__ dtb, const float* __restrict__ alog,
    float* __restrict__ xf, unsigned short* __restrict__ catb,
    float* __restrict__ delta, float* __restrict__ BC,
    float* __restrict__ P, float* __restrict__ H)
{
    __shared__ __align__(16) unsigned short Bs[160 * 136];
    __shared__ __align__(16) unsigned short As[64 * 136];
    __shared__ float bc_s[64 * 16];
    const int t = threadIdx.x;
    const int m0 = blockIdx.x * 64;
    for (int q = t; q < 2560; q += 256) {
        int n = q >> 4, kc = (q & 15) * 8;
        *(short8*)&Bs[n * 136 + kc] = *(const short8*)(Wb + n * 128 + kc);
    }
    #pragma unroll
    for (int i = 0; i < 8; ++i) {
        int s = t + i * 256;
        int r = s >> 5, g = s & 31;
        int gr = m0 + r;
        int l = gr & 4095;
        int c; const float* wp; const unsigned short* bp;
        if (g < 16) { c = g * 8;        wp = wx; bp = xz + (size_t)gr * 256 + c; }
        else        { c = (g - 16) * 8; wp = wz; bp = xz + (size_t)gr * 256 + 128 + c; }
        us8 zz = (us8)0;
        us8 vm = (l > 0)    ? *(const us8*)(bp - 256) : zz;
        us8 v0 = *(const us8*)bp;
        us8 vp = (l < 4095) ? *(const us8*)(bp + 256) : zz;
        float o[8];
        #pragma unroll
        for (int j = 0; j < 8; ++j) {
            int cc = c + j;
            float v = bf2f(vm[j]) * wp[cc * 3] + bf2f(v0[j]) * wp[cc * 3 + 1]
                    + bf2f(vp[j]) * wp[cc * 3 + 2];
            v = v / (1.f + __expf(-v));
            o[j] = v;
        }
        us8 rb8 = { f2bf(o[0]), f2bf(o[1]), f2bf(o[2]), f2bf(o[3]),
                    f2bf(o[4]), f2bf(o[5]), f2bf(o[6]), f2bf(o[7]) };
        if (g < 16) {
            *(us8*)&As[r * 136 + c] = rb8;
            *(f32x4*)&xf[(size_t)gr * 128 + c]     = *(f32x4*)&o[0];
            *(f32x4*)&xf[(size_t)gr * 128 + c + 4] = *(f32x4*)&o[4];
        } else {
            *(us8*)&catb[(size_t)gr * 256 + 128 + c] = rb8;
        }
    }
    __syncthreads();
    const int lane = t & 63, wv = t >> 6;
    const int lr = lane & 15, lk = (lane >> 4) * 8;
    f32x4 acc[10] = {};
    #pragma unroll
    for (int kt = 0; kt < 4; ++kt) {
        const int k0 = kt * 32;
        short8 av = *(const short8*)&As[(wv * 16 + lr) * 136 + k0 + lk];
        #pragma unroll
        for (int j = 0; j < 10; ++j) {
            short8 bv = *(const short8*)&Bs[(j * 16 + lr) * 136 + k0 + lk];
            acc[j] = __builtin_amdgcn_mfma_f32_16x16x32_bf16(av, bv, acc[j], 0, 0, 0);
        }
    }
    const int r0 = (lane >> 4) * 4;
    #pragma unroll
    for (int j = 0; j < 10; ++j) {
        int col = j * 16 + lr;
        #pragma unroll
        for (int r = 0; r < 4; ++r) {
            float v = acc[j][r];
            int lrow = wv * 16 + r0 + r;
            size_t row = (size_t)m0 + lrow;
            if (j < 8) {
                float x = v + dtb[col];
                float sp = (x > 20.f) ? x : log1pf(__expf(x));
                delta[row * 128 + col] = sp;
            } else {
                BC[row * 32 + (col - 128)] = v;
                if (FUSE_SCAN && j == 8) bc_s[lrow * 16 + lr] = v;   // B rows for scan
            }
        }
    }
    if (!FUSE_SCAN) return;

    // ---- scan phase-1 for this block's 2 chunks (32 rows each) ----
    __syncthreads();
    const int hh = t >> 7, tl = t & 127;
    const int sb = m0 >> 12;
    const int ch = ((m0 & 4095) >> 5) + hh;
    const size_t rb = (size_t)m0 + hh * 32;
    float Ar[16];
    #pragma unroll
    for (int n = 0; n < 16; ++n) Ar[n] = -__expf(alog[tl * 16 + n]) * LOG2E;
    float h[16], p[16];
    #pragma unroll
    for (int n = 0; n < 16; ++n) { h[n] = 0.f; p[n] = 1.f; }
    for (int i = 0; i < CH1; ++i) {
        float dt = delta[(rb + i) * DH + tl];   // L2-warm (written by this block)
        float uu = xf[(rb + i) * DH + tl];      // L2-warm
        float du = dt * uu;
        float bl[16];
        *(f32x4*)&bl[0]  = *(const f32x4*)&bc_s[(hh * 32 + i) * 16];
        *(f32x4*)&bl[4]  = *(const f32x4*)&bc_s[(hh * 32 + i) * 16 + 4];
        *(f32x4*)&bl[8]  = *(const f32x4*)&bc_s[(hh * 32 + i) * 16 + 8];
        *(f32x4*)&bl[12] = *(const f32x4*)&bc_s[(hh * 32 + i) * 16 + 12];
        #pragma unroll
        for (int n = 0; n < 16; ++n) {
            float a = exp2f(dt * Ar[n]);
            h[n] = fmaf(a, h[n], du * bl[n]);
            p[n] *= a;
        }
    }
    size_t ob = (((size_t)sb * NCH + ch) * 128 + tl) * 16;
    #pragma unroll
    for (int n4 = 0; n4 < 16; n4 += 4) {
        f32x4 pv = { p[n4], p[n4 + 1], p[n4 + 2], p[n4 + 3] };
        f32x4 hv = { h[n4], h[n4 + 1], h[n4 + 2], h[n4 + 3] };
        *(f32x4*)&P[ob + n4] = pv;
        *(f32x4*)&H[ob + n4] = hv;
    }
}

// ---------------- selective scan, chunked 3-phase, n-in-registers (standalone p1 = fallback) ----------------
__global__ __launch_bounds__(128) void scan_p1(
    const float* __restrict__ delta, const float* __restrict__ xf,
    const float* __restrict__ BC, const float* __restrict__ alog,
    float* __restrict__ P, float* __restrict__ H)
{
    __shared__ float dt_s[CH1 * 128];
    __shared__ float du_s[CH1 * 128];
    __shared__ float b_s[CH1 * 16];
    int t = threadIdx.x;                 // d channel
    int ch = blockIdx.x, sb = blockIdx.y;
    size_t rb = (size_t)sb * LL + (size_t)ch * CH1;
    for (int q = t; q < CH1 * 32; q += 128) {
        int row = q >> 5, c4 = (q & 31) * 4;
        f32x4 dv = *(const f32x4*)&delta[(rb + row) * DH + c4];
        f32x4 uv = *(const f32x4*)&xf[(rb + row) * DH + c4];
        *(f32x4*)&dt_s[row * 128 + c4] = dv;
        f32x4 duv = dv * uv;
        *(f32x4*)&du_s[row * 128 + c4] = duv;
    }
    {
        int q = t & 127;
        int row = q >> 2, c4 = (q & 3) * 4;
        *(f32x4*)&b_s[row * 16 + c4] = *(const f32x4*)&BC[(rb + row) * 32 + c4];
    }
    __syncthreads();
    float Ar[16];
    #pragma unroll
    for (int n = 0; n < 16; ++n) Ar[n] = -__expf(alog[t * 16 + n]) * LOG2E;
    float h[16], p[16];
    #pragma unroll
    for (int n = 0; n < 16; ++n) { h[n] = 0.f; p[n] = 1.f; }
    for (int i = 0; i < CH1; ++i) {
        float dt = dt_s[i * 128 + t];
        float du = du_s[i * 128 + t];
        float bl[16];
        *(f32x4*)&bl[0]  = *(const f32x4*)&b_s[i * 16];
        *(f32x4*)&bl[4]  = *(const f32x4*)&b_s[i * 16 + 4];
        *(f32x4*)&bl[8]  = *(const f32x4*)&b_s[i * 16 + 8];
        *(f32x4*)&bl[12] = *(const f32x4*)&b_s[i * 16 + 12];
        #pragma unroll
        for (int n = 0; n < 16; ++n) {
            float a = exp2f(dt * Ar[n]);
            h[n] = fmaf(a, h[n], du * bl[n]);
            p[n] *= a;
        }
    }
    size_t ob = (((size_t)sb * NCH + ch) * 128 + t) * 16;
    #pragma unroll
    for (int n4 = 0; n4 < 16; n4 += 4) {
        f32x4 pv = { p[n4], p[n4 + 1], p[n4 + 2], p[n4 + 3] };
        f32x4 hv = { h[n4], h[n4 + 1], h[n4 + 2], h[n4 + 3] };
        *(f32x4*)&P[ob + n4] = pv;
        *(f32x4*)&H[ob + n4] = hv;
    }
}

__global__ __launch_bounds__(256) void scan_p2(const float* __restrict__ P, float* __restrict__ H)
{
    __shared__ float Ps[NCH * 16], Hs[NCH * 16];
    int t = threadIdx.x;
    int d = blockIdx.x, sb = blockIdx.y;
    for (int q = t; q < NCH * 4; q += 256) {
        int ch = q >> 2, c4 = (q & 3) * 4;
        size_t g = (((size_t)sb * NCH + ch) * 128 + d) * 16 + c4;
        *(f32x4*)&Ps[ch * 16 + c4] = *(const f32x4*)&P[g];
        *(f32x4*)&Hs[ch * 16 + c4] = *(const f32x4*)&H[g];
    }
    __syncthreads();
    if (t < 16) {
        float hin = 0.f;
        for (int c = 0; c < NCH; ++c) {
            float pp = Ps[c * 16 + t], hl = Hs[c * 16 + t];
            Hs[c * 16 + t] = hin;
            hin = fmaf(pp, hin, hl);
        }
    }
    __syncthreads();
    for (int q = t; q < NCH * 4; q += 256) {
        int ch = q >> 2, c4 = (q & 3) * 4;
        size_t g = (((size_t)sb * NCH + ch) * 128 + d) * 16 + c4;
        *(f32x4*)&H[g] = *(const f32x4*)&Hs[ch * 16 + c4];
    }
}

__global__ __launch_bounds__(128) void scan_p3(
    const float* __restrict__ delta, const float* __restrict__ xf,
    const float* __restrict__ BC, const float* __restrict__ alog,
    const float* __restrict__ Dp, const float* __restrict__ H,
    unsigned short* __restrict__ catb)
{
    __shared__ float dt_s[CH1 * 128];
    __shared__ float u_s[CH1 * 128];
    __shared__ float b_s[CH1 * 16];
    __shared__ float c_s[CH1 * 16];
    int t = threadIdx.x;
    int ch = blockIdx.x, sb = blockIdx.y;
    size_t rb = (size_t)sb * LL + (size_t)ch * CH1;
    for (int q = t; q < CH1 * 32; q += 128) {
        int row = q >> 5, c4 = (q & 31) * 4;
        *(f32x4*)&dt_s[row * 128 + c4] = *(const f32x4*)&delta[(rb + row) * DH + c4];
        *(f32x4*)&u_s[row * 128 + c4]  = *(const f32x4*)&xf[(rb + row) * DH + c4];
    }
    {
        int q = t & 127;
        int row = q >> 2, c4 = (q & 3) * 4;
        *(f32x4*)&b_s[row * 16 + c4] = *(const f32x4*)&BC[(rb + row) * 32 + c4];
        *(f32x4*)&c_s[row * 16 + c4] = *(const f32x4*)&BC[(rb + row) * 32 + 16 + c4];
    }
    __syncthreads();
    float Ar[16];
    #pragma unroll
    for (int n = 0; n < 16; ++n) Ar[n] = -__expf(alog[t * 16 + n]) * LOG2E;
    float Dv = Dp[t];
    size_t ob = (((size_t)sb * NCH + ch) * 128 + t) * 16;
    float h[16];
    #pragma unroll
    for (int n4 = 0; n4 < 16; n4 += 4) {
        f32x4 hv = *(const f32x4*)&H[ob + n4];
        h[n4] = hv.x; h[n4 + 1] = hv.y; h[n4 + 2] = hv.z; h[n4 + 3] = hv.w;
    }
    for (int i = 0; i < CH1; ++i) {
        float dt = dt_s[i * 128 + t];
        float uu = u_s[i * 128 + t];
        float du = dt * uu;
        float bl[16], cl[16];
        *(f32x4*)&bl[0]  = *(const f32x4*)&b_s[i * 16];
        *(f32x4*)&bl[4]  = *(const f32x4*)&b_s[i * 16 + 4];
        *(f32x4*)&bl[8]  = *(const f32x4*)&b_s[i * 16 + 8];
        *(f32x4*)&bl[12] = *(const f32x4*)&b_s[i * 16 + 12];
        *(f32x4*)&cl[0]  = *(const f32x4*)&c_s[i * 16];
        *(f32x4*)&cl[4]  = *(const f32x4*)&c_s[i * 16 + 4];
        *(f32x4*)&cl[8]  = *(const f32x4*)&c_s[i * 16 + 8];
        *(f32x4*)&cl[12] = *(const f32x4*)&c_s[i * 16 + 12];
        float y0 = uu * Dv, y1 = 0.f, y2 = 0.f, y3 = 0.f;
        #pragma unroll
        for (int n = 0; n < 16; n += 4) {
            float a0 = exp2f(dt * Ar[n]);
            float a1 = exp2f(dt * Ar[n + 1]);
            float a2 = exp2f(dt * Ar[n + 2]);
            float a3 = exp2f(dt * Ar[n + 3]);
            h[n]     = fmaf(a0, h[n],     du * bl[n]);
            h[n + 1] = fmaf(a1, h[n + 1], du * bl[n + 1]);
            h[n + 2] = fmaf(a2, h[n + 2], du * bl[n + 2]);
            h[n + 3] = fmaf(a3, h[n + 3], du * bl[n + 3]);
            y0 = fmaf(h[n],     cl[n],     y0);
            y1 = fmaf(h[n + 1], cl[n + 1], y1);
            y2 = fmaf(h[n + 2], cl[n + 2], y2);
            y3 = fmaf(h[n + 3], cl[n + 3], y3);
        }
        float y = (y0 + y1) + (y2 + y3);
        catb[(rb + i) * DM + t] = f2bf(y);
    }
}

extern "C" void kernel_launch(void* const* d_in, const int* in_sizes, int n_in,
                              void* d_out, int out_size, void* d_ws, size_t ws_size,
                              hipStream_t stream) {
    const float* u0   = (const float*)d_in[0];
    const float* u1   = (const float*)d_in[1];
    const float* inw  = (const float*)d_in[2];
    const float* cxw  = (const float*)d_in[3];
    const float* czw  = (const float*)d_in[4];
    const float* xpw  = (const float*)d_in[5];
    const float* dtw  = (const float*)d_in[6];
    const float* dtb  = (const float*)d_in[7];
    const float* alog = (const float*)d_in[8];
    const float* Dp   = (const float*)d_in[9];
    const float* outw = (const float*)d_in[10];

    // Base layout (identical to verified R3):
    //   [0 : 16.8M]      ubf (prep->gemm1), then delta (convproj..scan_p3)
    //   [16.8M : 33.6M]  xzbf (gemm1->convproj)   [fallback: then P/H]
    //   [33.6M : 50.3M]  xf f32
    //   [50.3M : 54.5M]  BC
    //   [54.5M : 71.3M]  catb
    //   [71.3M : 71.6M]  wbi, wbo, Wb
    // Fused path only: P/H in fresh space [71.6M : 88.4M] (xzbf stays live during
    // convproj_k<1>, so P/H cannot alias it).
    char* ws = (char*)d_ws;
    unsigned short* ubf  = (unsigned short*)(ws + 0);
    float* delta         = (float*)(ws + 0);
    unsigned short* xzbf = (unsigned short*)(ws + 16777216);
    float* P_a           = (float*)(ws + 16777216);            // fallback P (over xzbf)
    float* H_a           = (float*)(ws + 25165824);            // fallback H
    float* xf            = (float*)(ws + 33554432);
    float* BC            = (float*)(ws + 50331648);
    unsigned short* catb = (unsigned short*)(ws + 54525952);
    unsigned short* wbi  = (unsigned short*)(ws + 71303168);
    unsigned short* wbo  = (unsigned short*)(ws + 71434240);
    unsigned short* Wb   = (unsigned short*)(ws + 71565312);   // +40,960 -> 71,606,272
    float* P_f           = (float*)(ws + 71606272);            //  8,388,608
    float* H_f           = (float*)(ws + 79994880);            //  8,388,608 -> 88,383,488

    float* outp = (float*)d_out;

    prep_kernel<<<8340, 256, 0, stream>>>(u0, u1, inw, outw, xpw, dtw, ubf, wbi, wbo, Wb);
    gemm_bt<0><<<dim3(256, 2), 256, 0, stream>>>(ubf, wbi, nullptr, xzbf);

    if (ws_size >= 88383488ull) {
        // fused conv+proj+scan_p1 (one fewer launch; scan reads are L2-warm)
        convproj_k<1><<<512, 256, 0, stream>>>(xzbf, Wb, cxw, czw, dtb, alog,
                                               xf, catb, delta, BC, P_f, H_f);
        scan_p2<<<dim3(128, 8), 256, 0, stream>>>(P_f, H_f);
        scan_p3<<<dim3(NCH, 8), 128, 0, stream>>>(delta, xf, BC, alog, Dp, H_f, catb);
    } else {
        // verified R3 path
        convproj_k<0><<<512, 256, 0, stream>>>(xzbf, Wb, cxw, czw, dtb, alog,
                                               xf, catb, delta, BC, nullptr, nullptr);
        scan_p1<<<dim3(NCH, 8), 128, 0, stream>>>(delta, xf, BC, alog, P_a, H_a);
        scan_p2<<<dim3(128, 8), 256, 0, stream>>>(P_a, H_a);
        scan_p3<<<dim3(NCH, 8), 128, 0, stream>>>(delta, xf, BC, alog, Dp, H_a, catb);
    }
    gemm_bt<1><<<dim3(256, 2), 256, 0, stream>>>(catb, wbo, outp, nullptr);
}

// Round 7
// 212.213 us; speedup vs baseline: 3.0428x; 1.0362x over previous
//
#include <hip/hip_runtime.h>
#include <hip/hip_bf16.h>
#include <cstdint>

#define DEV __device__ __forceinline__

typedef __attribute__((ext_vector_type(8))) short short8;
typedef __attribute__((ext_vector_type(4))) float f32x4;
typedef __attribute__((ext_vector_type(4))) unsigned short us4;
typedef __attribute__((ext_vector_type(8))) unsigned short us8;

DEV unsigned short f2bf(float x) {
    unsigned int u = __float_as_uint(x);
    unsigned int r = (u + 0x7FFFu + ((u >> 16) & 1u)) >> 16;
    return (unsigned short)r;
}
DEV float bf2f(unsigned short h) { return __uint_as_float(((unsigned int)h) << 16); }

// async global->LDS, 16B per lane; LDS dest is wave-uniform base + lane*16 (HW rule)
DEV void gld_lds16(const unsigned short* g, unsigned short* l) {
    __builtin_amdgcn_global_load_lds(
        (const __attribute__((address_space(1))) unsigned int*)g,
        (__attribute__((address_space(3))) unsigned int*)l, 16, 0, 0);
}

// problem sizes
#define LL 4096
#define DM 256
#define DH 128
#define SB_TOT 8       // 2 streams * 4 batch
#define CH1 32         // scan chunk length
#define NCH 128        // LL / CH1
#define LOG2E 1.44269504088896f

// ---------------- prep: fp32 -> bf16 (u, in_proj, out_proj) + fused proj weight Wb ----------------
// Wb[160][128] bf16:
//   n <  128 : Wb[n][k] = sum_r dtw[n][r] * xw[r][k]      (dt_proj folded into x_proj)
//   n >= 128 : Wb[n][k] = xw[16 + (n-128)][k]             (B and C rows)
__global__ __launch_bounds__(256) void prep_kernel(
    const float* __restrict__ u0, const float* __restrict__ u1,
    const float* __restrict__ inw, const float* __restrict__ outw,
    const float* __restrict__ xpw, const float* __restrict__ dtw,
    unsigned short* __restrict__ ubf, unsigned short* __restrict__ wbi,
    unsigned short* __restrict__ wbo, unsigned short* __restrict__ Wb)
{
    int gid = blockIdx.x * 256 + threadIdx.x;
    int i = gid * 4;
    if (i < 4194304) {
        f32x4 v = *(const f32x4*)&u0[i];
        us4 r = { f2bf(v.x), f2bf(v.y), f2bf(v.z), f2bf(v.w) };
        *(us4*)&ubf[i] = r;
    } else if (i < 8388608) {
        int j = i - 4194304;
        f32x4 v = *(const f32x4*)&u1[j];
        us4 r = { f2bf(v.x), f2bf(v.y), f2bf(v.z), f2bf(v.w) };
        *(us4*)&ubf[4194304 + j] = r;
    } else if (i < 8454144) {
        int j = i - 8388608;
        f32x4 v = *(const f32x4*)&inw[j];
        us4 r = { f2bf(v.x), f2bf(v.y), f2bf(v.z), f2bf(v.w) };
        *(us4*)&wbi[j] = r;
    } else if (i < 8519680) {
        int j = i - 8454144;
        f32x4 v = *(const f32x4*)&outw[j];
        us4 r = { f2bf(v.x), f2bf(v.y), f2bf(v.z), f2bf(v.w) };
        *(us4*)&wbo[j] = r;
    } else if (i < 8540160) {
        int j = i - 8519680;            // 0..20476, step 4
        int n = j >> 7, k0 = j & 127;
        if (n < 128) {
            float a0 = 0.f, a1 = 0.f, a2 = 0.f, a3 = 0.f;
            const float* dw = dtw + n * 16;
            #pragma unroll
            for (int r = 0; r < 16; ++r) {
                float w = dw[r];
                const float* xr = xpw + r * 128 + k0;
                a0 = fmaf(w, xr[0], a0);
                a1 = fmaf(w, xr[1], a1);
                a2 = fmaf(w, xr[2], a2);
                a3 = fmaf(w, xr[3], a3);
            }
            us4 rr = { f2bf(a0), f2bf(a1), f2bf(a2), f2bf(a3) };
            *(us4*)&Wb[n * 128 + k0] = rr;
        } else {
            f32x4 v = *(const f32x4*)&xpw[(n - 112) * 128 + k0];
            us4 rr = { f2bf(v.x), f2bf(v.y), f2bf(v.z), f2bf(v.w) };
            *(us4*)&Wb[n * 128 + k0] = rr;
        }
    }
}

// ---------------- bf16 MFMA GEMM (m97 structure): C[M,N] = A[M,K] * B[N,K]^T, K=N=256 ----------------
template<int F32OUT>
__global__ __launch_bounds__(256) void gemm_bt(
    const unsigned short* __restrict__ A, const unsigned short* __restrict__ B,
    float* __restrict__ Cf, unsigned short* __restrict__ Cb)
{
    __shared__ __align__(16) unsigned short As[128 * 32];
    __shared__ __align__(16) unsigned short Bs[128 * 32];
    const int t = threadIdx.x;
    const int m0 = blockIdx.x * 128, n0 = blockIdx.y * 128;
    const int lane = t & 63, wv = t >> 6;
    const int wm = (wv & 1) * 64, wn = (wv >> 1) * 64;
    const int lr = lane & 15, lk = (lane >> 4) * 8;
    const int srow = lane >> 2, scol = (lane & 3) * 8;

    f32x4 acc[4][4] = {};
    for (int kt = 0; kt < 8; ++kt) {
        const int k0 = kt * 32;
        #pragma unroll
        for (int h = 0; h < 2; ++h) {
            const int c = wv + h * 4;
            const unsigned short* ga = A + (size_t)(m0 + c * 16 + srow) * 256 + k0 + scol;
            const unsigned short* gb = B + (size_t)(n0 + c * 16 + srow) * 256 + k0 + scol;
            gld_lds16(ga, &As[c * 512]);
            gld_lds16(gb, &Bs[c * 512]);
        }
        __syncthreads();
        short8 av[4], bv[4];
        #pragma unroll
        for (int i = 0; i < 4; ++i) av[i] = *(const short8*)&As[(wm + i * 16 + lr) * 32 + lk];
        #pragma unroll
        for (int i = 0; i < 4; ++i) bv[i] = *(const short8*)&Bs[(wn + i * 16 + lr) * 32 + lk];
        #pragma unroll
        for (int i = 0; i < 4; ++i)
            #pragma unroll
            for (int j = 0; j < 4; ++j)
                acc[i][j] = __builtin_amdgcn_mfma_f32_16x16x32_bf16(av[i], bv[j], acc[i][j], 0, 0, 0);
        __syncthreads();
    }
    #pragma unroll
    for (int i = 0; i < 4; ++i) {
        #pragma unroll
        for (int j = 0; j < 4; ++j) {
            int r0 = m0 + wm + i * 16 + (lane >> 4) * 4;
            int cc = n0 + wn + j * 16 + lr;
            #pragma unroll
            for (int r = 0; r < 4; ++r) {
                float v = acc[i][j][r];
                if (F32OUT) Cf[(size_t)(r0 + r) * 256 + cc] = v;
                else        Cb[(size_t)(r0 + r) * 256 + cc] = f2bf(v);
            }
        }
    }
}

// ---------------- fused depthwise conv + SiLU + x_proj/dt_proj MFMA + softplus ----------------
// B-operand fragments read directly from global Wb (40KB, L2-resident across all blocks;
// pattern verified in R5). LDS only As + bc_s (~21.5KB) -> high occupancy.
// FUSE_SCAN=1 additionally runs scan phase-1 for this block's 2 chunks.
template<int FUSE_SCAN>
__global__ __launch_bounds__(256) void convproj_k(
    const unsigned short* __restrict__ xz, const unsigned short* __restrict__ Wb,
    const float* __restrict__ wx, const float* __restrict__ wz,
    const float* __restrict__ dtb, const float* __restrict__ alog,
    float* __restrict__ xf, unsigned short* __restrict__ catb,
    float* __restrict__ delta, float* __restrict__ BC,
    float* __restrict__ P, float* __restrict__ H)
{
    __shared__ __align__(16) unsigned short As[64 * 136];
    __shared__ float bc_s[64 * 16];
    const int t = threadIdx.x;
    const int m0 = blockIdx.x * 64;
    #pragma unroll
    for (int i = 0; i < 8; ++i) {
        int s = t + i * 256;
        int r = s >> 5, g = s & 31;
        int gr = m0 + r;
        int l = gr & 4095;
        int c; const float* wp; const unsigned short* bp;
        if (g < 16) { c = g * 8;        wp = wx; bp = xz + (size_t)gr * 256 + c; }
        else        { c = (g - 16) * 8; wp = wz; bp = xz + (size_t)gr * 256 + 128 + c; }
        us8 zz = (us8)0;
        us8 vm = (l > 0)    ? *(const us8*)(bp - 256) : zz;
        us8 v0 = *(const us8*)bp;
        us8 vp = (l < 4095) ? *(const us8*)(bp + 256) : zz;
        float o[8];
        #pragma unroll
        for (int j = 0; j < 8; ++j) {
            int cc = c + j;
            float v = bf2f(vm[j]) * wp[cc * 3] + bf2f(v0[j]) * wp[cc * 3 + 1]
                    + bf2f(vp[j]) * wp[cc * 3 + 2];
            v = v / (1.f + __expf(-v));
            o[j] = v;
        }
        us8 rb8 = { f2bf(o[0]), f2bf(o[1]), f2bf(o[2]), f2bf(o[3]),
                    f2bf(o[4]), f2bf(o[5]), f2bf(o[6]), f2bf(o[7]) };
        if (g < 16) {
            *(us8*)&As[r * 136 + c] = rb8;
            *(f32x4*)&xf[(size_t)gr * 128 + c]     = *(f32x4*)&o[0];
            *(f32x4*)&xf[(size_t)gr * 128 + c + 4] = *(f32x4*)&o[4];
        } else {
            *(us8*)&catb[(size_t)gr * 256 + 128 + c] = rb8;
        }
    }
    __syncthreads();
    const int lane = t & 63, wv = t >> 6;
    const int lr = lane & 15, lk = (lane >> 4) * 8;
    f32x4 acc[10] = {};
    #pragma unroll
    for (int kt = 0; kt < 4; ++kt) {
        const int k0 = kt * 32;
        short8 av = *(const short8*)&As[(wv * 16 + lr) * 136 + k0 + lk];
        #pragma unroll
        for (int j = 0; j < 10; ++j) {
            short8 bv = *(const short8*)(Wb + (j * 16 + lr) * 128 + k0 + lk);
            acc[j] = __builtin_amdgcn_mfma_f32_16x16x32_bf16(av, bv, acc[j], 0, 0, 0);
        }
    }
    const int r0 = (lane >> 4) * 4;
    #pragma unroll
    for (int j = 0; j < 10; ++j) {
        int col = j * 16 + lr;
        #pragma unroll
        for (int r = 0; r < 4; ++r) {
            float v = acc[j][r];
            int lrow = wv * 16 + r0 + r;
            size_t row = (size_t)m0 + lrow;
            if (j < 8) {
                float x = v + dtb[col];
                float sp = (x > 20.f) ? x : __logf(1.f + __expf(x));
                delta[row * 128 + col] = sp;
            } else {
                BC[row * 32 + (col - 128)] = v;
                if (FUSE_SCAN && j == 8) bc_s[lrow * 16 + lr] = v;   // B rows for scan
            }
        }
    }
    if (!FUSE_SCAN) return;

    // ---- scan phase-1 for this block's 2 chunks (32 rows each) ----
    __syncthreads();
    const int hh = t >> 7, tl = t & 127;
    const int sb = m0 >> 12;
    const int ch = ((m0 & 4095) >> 5) + hh;
    const size_t rb = (size_t)m0 + hh * 32;
    float Ar[16];
    #pragma unroll
    for (int n = 0; n < 16; ++n) Ar[n] = -__expf(alog[tl * 16 + n]) * LOG2E;
    float h[16], p[16];
    #pragma unroll
    for (int n = 0; n < 16; ++n) { h[n] = 0.f; p[n] = 1.f; }
    for (int i = 0; i < CH1; ++i) {
        float dt = delta[(rb + i) * DH + tl];   // L2-warm (written by this block)
        float uu = xf[(rb + i) * DH + tl];      // L2-warm
        float du = dt * uu;
        float bl[16];
        *(f32x4*)&bl[0]  = *(const f32x4*)&bc_s[(hh * 32 + i) * 16];
        *(f32x4*)&bl[4]  = *(const f32x4*)&bc_s[(hh * 32 + i) * 16 + 4];
        *(f32x4*)&bl[8]  = *(const f32x4*)&bc_s[(hh * 32 + i) * 16 + 8];
        *(f32x4*)&bl[12] = *(const f32x4*)&bc_s[(hh * 32 + i) * 16 + 12];
        #pragma unroll
        for (int n = 0; n < 16; ++n) {
            float a = exp2f(dt * Ar[n]);
            h[n] = fmaf(a, h[n], du * bl[n]);
            p[n] *= a;
        }
    }
    size_t ob = (((size_t)sb * NCH + ch) * 128 + tl) * 16;
    #pragma unroll
    for (int n4 = 0; n4 < 16; n4 += 4) {
        f32x4 pv = { p[n4], p[n4 + 1], p[n4 + 2], p[n4 + 3] };
        f32x4 hv = { h[n4], h[n4 + 1], h[n4 + 2], h[n4 + 3] };
        *(f32x4*)&P[ob + n4] = pv;
        *(f32x4*)&H[ob + n4] = hv;
    }
}

// ---------------- selective scan, chunked 3-phase, n-in-registers (standalone p1 = fallback) ----------------
__global__ __launch_bounds__(128) void scan_p1(
    const float* __restrict__ delta, const float* __restrict__ xf,
    const float* __restrict__ BC, const float* __restrict__ alog,
    float* __restrict__ P, float* __restrict__ H)
{
    __shared__ float dt_s[CH1 * 128];
    __shared__ float du_s[CH1 * 128];
    __shared__ float b_s[CH1 * 16];
    int t = threadIdx.x;                 // d channel
    int ch = blockIdx.x, sb = blockIdx.y;
    size_t rb = (size_t)sb * LL + (size_t)ch * CH1;
    for (int q = t; q < CH1 * 32; q += 128) {
        int row = q >> 5, c4 = (q & 31) * 4;
        f32x4 dv = *(const f32x4*)&delta[(rb + row) * DH + c4];
        f32x4 uv = *(const f32x4*)&xf[(rb + row) * DH + c4];
        *(f32x4*)&dt_s[row * 128 + c4] = dv;
        f32x4 duv = dv * uv;
        *(f32x4*)&du_s[row * 128 + c4] = duv;
    }
    {
        int q = t & 127;
        int row = q >> 2, c4 = (q & 3) * 4;
        *(f32x4*)&b_s[row * 16 + c4] = *(const f32x4*)&BC[(rb + row) * 32 + c4];
    }
    __syncthreads();
    float Ar[16];
    #pragma unroll
    for (int n = 0; n < 16; ++n) Ar[n] = -__expf(alog[t * 16 + n]) * LOG2E;
    float h[16], p[16];
    #pragma unroll
    for (int n = 0; n < 16; ++n) { h[n] = 0.f; p[n] = 1.f; }
    for (int i = 0; i < CH1; ++i) {
        float dt = dt_s[i * 128 + t];
        float du = du_s[i * 128 + t];
        float bl[16];
        *(f32x4*)&bl[0]  = *(const f32x4*)&b_s[i * 16];
        *(f32x4*)&bl[4]  = *(const f32x4*)&b_s[i * 16 + 4];
        *(f32x4*)&bl[8]  = *(const f32x4*)&b_s[i * 16 + 8];
        *(f32x4*)&bl[12] = *(const f32x4*)&b_s[i * 16 + 12];
        #pragma unroll
        for (int n = 0; n < 16; ++n) {
            float a = exp2f(dt * Ar[n]);
            h[n] = fmaf(a, h[n], du * bl[n]);
            p[n] *= a;
        }
    }
    size_t ob = (((size_t)sb * NCH + ch) * 128 + t) * 16;
    #pragma unroll
    for (int n4 = 0; n4 < 16; n4 += 4) {
        f32x4 pv = { p[n4], p[n4 + 1], p[n4 + 2], p[n4 + 3] };
        f32x4 hv = { h[n4], h[n4 + 1], h[n4 + 2], h[n4 + 3] };
        *(f32x4*)&P[ob + n4] = pv;
        *(f32x4*)&H[ob + n4] = hv;
    }
}

__global__ __launch_bounds__(256) void scan_p2(const float* __restrict__ P, float* __restrict__ H)
{
    __shared__ float Ps[NCH * 16], Hs[NCH * 16];
    int t = threadIdx.x;
    int d = blockIdx.x, sb = blockIdx.y;
    for (int q = t; q < NCH * 4; q += 256) {
        int ch = q >> 2, c4 = (q & 3) * 4;
        size_t g = (((size_t)sb * NCH + ch) * 128 + d) * 16 + c4;
        *(f32x4*)&Ps[ch * 16 + c4] = *(const f32x4*)&P[g];
        *(f32x4*)&Hs[ch * 16 + c4] = *(const f32x4*)&H[g];
    }
    __syncthreads();
    if (t < 16) {
        float hin = 0.f;
        for (int c = 0; c < NCH; ++c) {
            float pp = Ps[c * 16 + t], hl = Hs[c * 16 + t];
            Hs[c * 16 + t] = hin;
            hin = fmaf(pp, hin, hl);
        }
    }
    __syncthreads();
    for (int q = t; q < NCH * 4; q += 256) {
        int ch = q >> 2, c4 = (q & 3) * 4;
        size_t g = (((size_t)sb * NCH + ch) * 128 + d) * 16 + c4;
        *(f32x4*)&H[g] = *(const f32x4*)&Hs[ch * 16 + c4];
    }
}

__global__ __launch_bounds__(128) void scan_p3(
    const float* __restrict__ delta, const float* __restrict__ xf,
    const float* __restrict__ BC, const float* __restrict__ alog,
    const float* __restrict__ Dp, const float* __restrict__ H,
    unsigned short* __restrict__ catb)
{
    __shared__ float dt_s[CH1 * 128];
    __shared__ float u_s[CH1 * 128];
    __shared__ float b_s[CH1 * 16];
    __shared__ float c_s[CH1 * 16];
    int t = threadIdx.x;
    int ch = blockIdx.x, sb = blockIdx.y;
    size_t rb = (size_t)sb * LL + (size_t)ch * CH1;
    for (int q = t; q < CH1 * 32; q += 128) {
        int row = q >> 5, c4 = (q & 31) * 4;
        *(f32x4*)&dt_s[row * 128 + c4] = *(const f32x4*)&delta[(rb + row) * DH + c4];
        *(f32x4*)&u_s[row * 128 + c4]  = *(const f32x4*)&xf[(rb + row) * DH + c4];
    }
    {
        int q = t & 127;
        int row = q >> 2, c4 = (q & 3) * 4;
        *(f32x4*)&b_s[row * 16 + c4] = *(const f32x4*)&BC[(rb + row) * 32 + c4];
        *(f32x4*)&c_s[row * 16 + c4] = *(const f32x4*)&BC[(rb + row) * 32 + 16 + c4];
    }
    __syncthreads();
    float Ar[16];
    #pragma unroll
    for (int n = 0; n < 16; ++n) Ar[n] = -__expf(alog[t * 16 + n]) * LOG2E;
    float Dv = Dp[t];
    size_t ob = (((size_t)sb * NCH + ch) * 128 + t) * 16;
    float h[16];
    #pragma unroll
    for (int n4 = 0; n4 < 16; n4 += 4) {
        f32x4 hv = *(const f32x4*)&H[ob + n4];
        h[n4] = hv.x; h[n4 + 1] = hv.y; h[n4 + 2] = hv.z; h[n4 + 3] = hv.w;
    }
    for (int i = 0; i < CH1; ++i) {
        float dt = dt_s[i * 128 + t];
        float uu = u_s[i * 128 + t];
        float du = dt * uu;
        float bl[16], cl[16];
        *(f32x4*)&bl[0]  = *(const f32x4*)&b_s[i * 16];
        *(f32x4*)&bl[4]  = *(const f32x4*)&b_s[i * 16 + 4];
        *(f32x4*)&bl[8]  = *(const f32x4*)&b_s[i * 16 + 8];
        *(f32x4*)&bl[12] = *(const f32x4*)&b_s[i * 16 + 12];
        *(f32x4*)&cl[0]  = *(const f32x4*)&c_s[i * 16];
        *(f32x4*)&cl[4]  = *(const f32x4*)&c_s[i * 16 + 4];
        *(f32x4*)&cl[8]  = *(const f32x4*)&c_s[i * 16 + 8];
        *(f32x4*)&cl[12] = *(const f32x4*)&c_s[i * 16 + 12];
        float y0 = uu * Dv, y1 = 0.f, y2 = 0.f, y3 = 0.f;
        #pragma unroll
        for (int n = 0; n < 16; n += 4) {
            float a0 = exp2f(dt * Ar[n]);
            float a1 = exp2f(dt * Ar[n + 1]);
            float a2 = exp2f(dt * Ar[n + 2]);
            float a3 = exp2f(dt * Ar[n + 3]);
            h[n]     = fmaf(a0, h[n],     du * bl[n]);
            h[n + 1] = fmaf(a1, h[n + 1], du * bl[n + 1]);
            h[n + 2] = fmaf(a2, h[n + 2], du * bl[n + 2]);
            h[n + 3] = fmaf(a3, h[n + 3], du * bl[n + 3]);
            y0 = fmaf(h[n],     cl[n],     y0);
            y1 = fmaf(h[n + 1], cl[n + 1], y1);
            y2 = fmaf(h[n + 2], cl[n + 2], y2);
            y3 = fmaf(h[n + 3], cl[n + 3], y3);
        }
        float y = (y0 + y1) + (y2 + y3);
        catb[(rb + i) * DM + t] = f2bf(y);
    }
}

extern "C" void kernel_launch(void* const* d_in, const int* in_sizes, int n_in,
                              void* d_out, int out_size, void* d_ws, size_t ws_size,
                              hipStream_t stream) {
    const float* u0   = (const float*)d_in[0];
    const float* u1   = (const float*)d_in[1];
    const float* inw  = (const float*)d_in[2];
    const float* cxw  = (const float*)d_in[3];
    const float* czw  = (const float*)d_in[4];
    const float* xpw  = (const float*)d_in[5];
    const float* dtw  = (const float*)d_in[6];
    const float* dtb  = (const float*)d_in[7];
    const float* alog = (const float*)d_in[8];
    const float* Dp   = (const float*)d_in[9];
    const float* outw = (const float*)d_in[10];

    // Base layout (identical to verified R3):
    //   [0 : 16.8M]      ubf (prep->gemm1), then delta (convproj..scan_p3)
    //   [16.8M : 33.6M]  xzbf (gemm1->convproj)   [fallback: then P/H]
    //   [33.6M : 50.3M]  xf f32
    //   [50.3M : 54.5M]  BC
    //   [54.5M : 71.3M]  catb
    //   [71.3M : 71.6M]  wbi, wbo, Wb
    // Fused path only: P/H in fresh space [71.6M : 88.4M] (xzbf stays live during
    // convproj_k<1>, so P/H cannot alias it).
    char* ws = (char*)d_ws;
    unsigned short* ubf  = (unsigned short*)(ws + 0);
    float* delta         = (float*)(ws + 0);
    unsigned short* xzbf = (unsigned short*)(ws + 16777216);
    float* P_a           = (float*)(ws + 16777216);            // fallback P (over xzbf)
    float* H_a           = (float*)(ws + 25165824);            // fallback H
    float* xf            = (float*)(ws + 33554432);
    float* BC            = (float*)(ws + 50331648);
    unsigned short* catb = (unsigned short*)(ws + 54525952);
    unsigned short* wbi  = (unsigned short*)(ws + 71303168);
    unsigned short* wbo  = (unsigned short*)(ws + 71434240);
    unsigned short* Wb   = (unsigned short*)(ws + 71565312);   // +40,960 -> 71,606,272
    float* P_f           = (float*)(ws + 71606272);            //  8,388,608
    float* H_f           = (float*)(ws + 79994880);            //  8,388,608 -> 88,383,488

    float* outp = (float*)d_out;

    prep_kernel<<<8340, 256, 0, stream>>>(u0, u1, inw, outw, xpw, dtw, ubf, wbi, wbo, Wb);
    gemm_bt<0><<<dim3(256, 2), 256, 0, stream>>>(ubf, wbi, nullptr, xzbf);

    if (ws_size >= 88383488ull) {
        // fused conv+proj+scan_p1 (one fewer launch; scan reads are L2-warm)
        convproj_k<1><<<512, 256, 0, stream>>>(xzbf, Wb, cxw, czw, dtb, alog,
                                               xf, catb, delta, BC, P_f, H_f);
        scan_p2<<<dim3(128, 8), 256, 0, stream>>>(P_f, H_f);
        scan_p3<<<dim3(NCH, 8), 128, 0, stream>>>(delta, xf, BC, alog, Dp, H_f, catb);
    } else {
        // verified R3 path
        convproj_k<0><<<512, 256, 0, stream>>>(xzbf, Wb, cxw, czw, dtb, alog,
                                               xf, catb, delta, BC, nullptr, nullptr);
        scan_p1<<<dim3(NCH, 8), 128, 0, stream>>>(delta, xf, BC, alog, P_a, H_a);
        scan_p2<<<dim3(128, 8), 256, 0, stream>>>(P_a, H_a);
        scan_p3<<<dim3(NCH, 8), 128, 0, stream>>>(delta, xf, BC, alog, Dp, H_a, catb);
    }
    gemm_bt<1><<<dim3(256, 2), 256, 0, stream>>>(catb, wbo, outp, nullptr);
}